// Round 18
// baseline (219.098 us; speedup 1.0000x reference)
//
#include <hip/hip_runtime.h>
#include <hip/hip_bf16.h>

// GNN attention layer. V=50000, E=800000, D=H=128. Inputs f32, OUTPUT f32.
//
// R29: R28 landed (217.5->207.2); no kernel of ours > 40 us; sum of kernels
// ~150 us vs 207 total => ~57 us of launch serialization/tails across 8
// dispatches. Consolidate: (1) fold hist blocks into conv_fused (hist depends
// only on input dst; results not read until scan_a) -> hist's latency work
// overlaps conv's BW streaming, np_hist becomes np-only (LDS 33->8 KB);
// (2) delete probe kernel - each consumer block recomputes the 256-word
// dtype probe locally (same data -> same verdict); launches 8 -> 6;
// (3) aggregate depth 8 -> 12 (R27 lever, +36 VGPR, occ unaffected).
// Rest = R28 (LDS-DMA pipelines in np+gru, XCD swizzles, fused scans,
// counting sort, atomic-free scatter).

#define V_NODES 50000
#define E_EDGES 800000
#define D_FEAT  128
#define GCHUNK  5             // tiles per chunk (625 chunks x 8 cg = 5000 tasks)
#define WS_BLOCKS 1250        // np: 5000 waves / 4 per block
#define GRU_BLOCKS 1264       // gru: 8 xcds x 158 slots (2 blocks/chunk, guard)

#define NCHUNK  49            // ceil(800000/16384) edge chunks
#define CHUNK_E 16384         // edges per chunk (e >> 14)
#define RANGES  4             // node ranges per chunk
#define NODE_R  12500         // nodes per range (25 KB packed LDS histogram)
#define HISTG   (NCHUNK * RANGES)   // 196 hist blocks
#define SCAN_BLOCKS 196       // ceil(50000/256)

typedef short bf16x8 __attribute__((ext_vector_type(8)));  // 8 bf16 in 4 VGPRs
typedef float f32x4  __attribute__((ext_vector_type(4)));
typedef unsigned short u16x4 __attribute__((ext_vector_type(4)));

// small-tensor bf16 pool element offsets
#define OFF_WEDGE 0
#define OFF_WPROJ 256
#define OFF_WIH   16640
#define OFF_WHH   65792
#define OFF_BEDGE 114944
#define OFF_BPROJ 114945
#define OFF_BIH   115073
#define OFF_BHH   115457
#define SMALL_TOTAL 115841
#define CONV_X_BLOCKS   6250   // 1.6M u16x4 / 256
#define CONV_S_BLOCKS   453
#define HIST_BLOCKS     3125   // 800000/256 (edge scatter grid)

// ---- device-global scratch (~58 MB; immune to ws_size) ----
__device__ float g_pd[V_NODES];
__device__ float g_ps[V_NODES];
__device__ __attribute__((aligned(16))) unsigned int g_mat[NCHUNK * V_NODES]; // counts -> bases
__device__ int   g_row_off[V_NODES + 1];
__device__ int   g_blocksum[SCAN_BLOCKS];
__device__ unsigned short g_rank16[E_EDGES];    // within-chunk rank
__device__ __attribute__((aligned(16))) int2 g_s_pair[E_EDGES];  // {src, bits(w)}
__device__ __attribute__((aligned(16))) unsigned short g_xbf[V_NODES * D_FEAT];
__device__ __attribute__((aligned(16))) unsigned short g_wsmall[SMALL_TOTAL + 15];
__device__ __attribute__((aligned(16))) unsigned short g_hv[V_NODES * D_FEAT];
__device__ __attribute__((aligned(16))) unsigned short g_ctx[V_NODES * D_FEAT];

static __device__ __forceinline__ float b2f(unsigned short u) {
  union { unsigned int i; float f; } v; v.i = ((unsigned int)u) << 16; return v.f;
}
static __device__ __forceinline__ unsigned short f2b(float f) {
  unsigned int i = __float_as_uint(f);
  unsigned int r = (i + 0x7FFFu + ((i >> 16) & 1u)) >> 16;  // RNE (NaN stays NaN)
  return (unsigned short)r;
}
static __device__ __forceinline__ bf16x8 load_frag(const unsigned short* p) {
  return *reinterpret_cast<const bf16x8*>(p);  // 16B-aligned vector load
}
static __device__ __forceinline__ float fast_rcp(float x) {
  return __builtin_amdgcn_rcpf(x);             // v_rcp_f32, ~1 ulp
}
static __device__ __forceinline__ float fast_sigmoid(float x) {
  return fast_rcp(1.f + __expf(-x));           // x<<0: exp->inf, rcp->0. ok
}
static __device__ __forceinline__ float fast_tanh(float y) {
  // 1 - 2/(e^{2y}+1); y>>0: exp->inf, rcp->0 -> 1; y<<0: exp->0 -> -1; NaN->NaN
  return 1.f - 2.f * fast_rcp(__expf(2.f * y) + 1.f);
}
// async global->LDS DMA, 16B per lane; lds ptr is wave-uniform base
static __device__ __forceinline__ void async_copy16(const void* g, void* l) {
  __builtin_amdgcn_global_load_lds(
      (const __attribute__((address_space(1))) void*)g,
      (__attribute__((address_space(3))) void*)l, 16, 0, 0);
}
// block-local dtype probe on first 256 words of x (same data -> same verdict
// in every block; replaces the old probe kernel). Must run with full block.
static __device__ __forceinline__ int block_probe(const unsigned int* xw,
                                                  int* pcnt) {
  if (threadIdx.x == 0) *pcnt = 0;
  __syncthreads();
  const unsigned int w  = xw[threadIdx.x];
  const unsigned int lo = w & 0xFFFFu;
  const unsigned int ex = (lo >> 7) & 0xFFu;
  if (lo != 0u && ex >= 118u && ex <= 132u) atomicAdd(pcnt, 1);
  __syncthreads();
  return (*pcnt >= 200) ? 1 : 0;
}

// ---------------- K0: fused convert-x | convert-smalls | hist ----------------
__global__ __launch_bounds__(256, 2) void conv_hist_kernel(
    const void* __restrict__ x, const int* __restrict__ dst,
    const void* p0, const void* p1, const void* p2, const void* p3,
    const void* p4, const void* p5, const void* p6, const void* p7)
{
  __shared__ unsigned int hloc[NODE_R / 2];  // 25 KB (hist); conv reuses [0]
  const int b = blockIdx.x;
  if (b < CONV_X_BLOCKS + CONV_S_BLOCKS) {   // ---- convert sections ----
    const int isb = block_probe(reinterpret_cast<const unsigned int*>(x),
                                reinterpret_cast<int*>(&hloc[0]));
    if (b < CONV_X_BLOCKS) {
      const int t = b * 256 + threadIdx.x;
      if (isb) {
        reinterpret_cast<u16x4*>(g_xbf)[t] = reinterpret_cast<const u16x4*>(x)[t];
      } else {
        const float4 v = reinterpret_cast<const float4*>(x)[t];
        u16x4 o; o.x = f2b(v.x); o.y = f2b(v.y); o.z = f2b(v.z); o.w = f2b(v.w);
        reinterpret_cast<u16x4*>(g_xbf)[t] = o;
      }
    } else {
      const int i = (b - CONV_X_BLOCKS) * 256 + threadIdx.x;
      if (i >= SMALL_TOTAL) return;
      const int offs[9] = {OFF_WEDGE, OFF_WPROJ, OFF_WIH, OFF_WHH,
                           OFF_BEDGE, OFF_BPROJ, OFF_BIH, OFF_BHH, SMALL_TOTAL};
      const void* ps[8] = {p0, p1, p2, p3, p4, p5, p6, p7};
      int r = 0;
#pragma unroll
      for (int k = 0; k < 8; k++) if (i >= offs[k]) r = k;
      const int j = i - offs[r];
      g_wsmall[i] = isb
          ? reinterpret_cast<const unsigned short*>(ps[r])[j]
          : f2b(reinterpret_cast<const float*>(ps[r])[j]);
    }
    return;
  }
  // ---- chunk x range histogram (depends only on dst; results read by
  //      scan_a two kernel boundaries later) ----
  const int hb = b - CONV_X_BLOCKS - CONV_S_BLOCKS;   // [0, HISTG)
  const int c  = hb >> 2;                    // chunk [0,49)
  const int r0 = (hb & 3) * NODE_R;          // range base node
  for (int i = threadIdx.x; i < NODE_R / 2; i += 256) hloc[i] = 0u;
  __syncthreads();
  const int ebase = c * CHUNK_E;
  const int ecnt  = min(CHUNK_E, E_EDGES - ebase);   // always multiple of 4
  const int4* dst4 = reinterpret_cast<const int4*>(dst + ebase);
  const int n4 = ecnt >> 2;
  for (int i = threadIdx.x; i < n4; i += 256) {
    const int4 d4 = dst4[i];                 // 4 edges per thread per iter
    const int e0 = ebase + (i << 2);
    const unsigned int rx = (unsigned int)(d4.x - r0);
    const unsigned int ry = (unsigned int)(d4.y - r0);
    const unsigned int rz = (unsigned int)(d4.z - r0);
    const unsigned int rw = (unsigned int)(d4.w - r0);
    if (rx < (unsigned int)NODE_R) {         // 4 independent atomics pipeline
      const unsigned int sh = (rx & 1u) << 4;
      const unsigned int old = atomicAdd(&hloc[rx >> 1], 1u << sh);
      g_rank16[e0] = (unsigned short)((old >> sh) & 0xFFFFu);
    }
    if (ry < (unsigned int)NODE_R) {
      const unsigned int sh = (ry & 1u) << 4;
      const unsigned int old = atomicAdd(&hloc[ry >> 1], 1u << sh);
      g_rank16[e0 + 1] = (unsigned short)((old >> sh) & 0xFFFFu);
    }
    if (rz < (unsigned int)NODE_R) {
      const unsigned int sh = (rz & 1u) << 4;
      const unsigned int old = atomicAdd(&hloc[rz >> 1], 1u << sh);
      g_rank16[e0 + 2] = (unsigned short)((old >> sh) & 0xFFFFu);
    }
    if (rw < (unsigned int)NODE_R) {
      const unsigned int sh = (rw & 1u) << 4;
      const unsigned int old = atomicAdd(&hloc[rw >> 1], 1u << sh);
      g_rank16[e0 + 3] = (unsigned short)((old >> sh) & 0xFFFFu);
    }
  }
  __syncthreads();
  // vectorized writeout: one hloc word -> uint2 {lo count, hi count}
  uint2* mout = reinterpret_cast<uint2*>(&g_mat[c * V_NODES + r0]);
  for (int i = threadIdx.x; i < NODE_R / 2; i += 256) {
    const unsigned int w = hloc[i];
    mout[i] = make_uint2(w & 0xFFFFu, w >> 16);
  }
}

// ---------------- K1: node_pre only (LDS-DMA tile pipeline) ------------------
__global__ __launch_bounds__(256, 2) void np_kernel()
{
  __shared__ __attribute__((aligned(16))) char lds_x[2][4096];  // x-tile dbuf
  const int b = blockIdx.x;
  // 4 waves share one chunk (g=4b+wid -> chunk block-uniform)
  const int wid   = threadIdx.x >> 6;
  const int g     = b * 4 + wid;
  const int lane  = threadIdx.x & 63;
  const int cg    = g & 7;
  const int chunk = g >> 3;                  // [0, 625), block-uniform
  const int col   = lane & 15;
  const int quad  = lane >> 4;
  const int h     = 16 * cg + col;

  // resident B fragments: W_proj rows [16cg, 16cg+16)
  bf16x8 bw[4];
#pragma unroll
  for (int kk = 0; kk < 4; kk++)
    bw[kk] = load_frag(g_wsmall + OFF_WPROJ + h * D_FEAT + kk * 32 + quad * 8);
  // cg 0 also owns the edge projections (cols 0/1 of W_edge)
  bf16x8 be[4];
#pragma unroll
  for (int kk = 0; kk < 4; kk++) { be[kk] = bf16x8{0,0,0,0,0,0,0,0}; }
  if (cg == 0 && col < 2) {
#pragma unroll
    for (int kk = 0; kk < 4; kk++)
      be[kk] = load_frag(g_wsmall + OFF_WEDGE + col * D_FEAT + kk * 32 + quad * 8);
  }
  const float bp = b2f(g_wsmall[OFF_BPROJ + h]);

  // staging addresses (R26-verified involution): linear LDS dest, swizzled
  // global source, swizzled ds_read returns the logical element.
  const int o_lin = wid * 1024 + lane * 16;
  const int o_src = o_lin ^ (((o_lin >> 8) & 7) << 4);
  const char* xbf_b = reinterpret_cast<const char*>(g_xbf);

  const int t0 = chunk * GCHUNK;
  async_copy16(xbf_b + (size_t)t0 * 4096 + o_src, &lds_x[0][wid * 1024]);

  for (int i = 0; i < GCHUNK; i++) {
    const int t = t0 + i;
    const int buf = i & 1;
    __syncthreads();   // implicit vmcnt(0): buf's DMA complete + visible
    bf16x8 a[4];
#pragma unroll
    for (int kk = 0; kk < 4; kk++) {
      const int phys = (col * 256 + kk * 64 + quad * 16) ^ ((col & 7) << 4);
      a[kk] = *reinterpret_cast<const bf16x8*>(&lds_x[buf][phys]);
    }
    if (i + 1 < GCHUNK)
      async_copy16(xbf_b + (size_t)(t + 1) * 4096 + o_src,
                   &lds_x[buf ^ 1][wid * 1024]);
    f32x4 acc; acc[0]=0.f; acc[1]=0.f; acc[2]=0.f; acc[3]=0.f;
#pragma unroll
    for (int kk = 0; kk < 4; kk++)
      acc = __builtin_amdgcn_mfma_f32_16x16x32_bf16(a[kk], bw[kk], acc, 0, 0, 0);
#pragma unroll
    for (int r = 0; r < 4; r++)
      g_hv[(t * 16 + quad * 4 + r) * D_FEAT + h] = f2b(acc[r] + bp);
    if (cg == 0) {
      f32x4 acce; acce[0]=0.f; acce[1]=0.f; acce[2]=0.f; acce[3]=0.f;
#pragma unroll
      for (int kk = 0; kk < 4; kk++)
        acce = __builtin_amdgcn_mfma_f32_16x16x32_bf16(a[kk], be[kk], acce, 0, 0, 0);
      if (col == 0) {
#pragma unroll
        for (int r = 0; r < 4; r++) g_pd[t * 16 + quad * 4 + r] = acce[r];
      } else if (col == 1) {
#pragma unroll
        for (int r = 0; r < 4; r++) g_ps[t * 16 + quad * 4 + r] = acce[r];
      }
    }
  }
}

// ---------------- K3a: column-sum over chunks + block-local scan --------------
__global__ __launch_bounds__(256) void scan_a_kernel()
{
  __shared__ int lds[256];
  const int b = blockIdx.x, t = threadIdx.x;
  const int idx = b * 256 + t;
  int v = 0;
  if (idx < V_NODES) {
#pragma unroll 7
    for (int c = 0; c < NCHUNK; c++) v += (int)g_mat[c * V_NODES + idx];
  }
  lds[t] = v;
  __syncthreads();
  for (int off = 1; off < 256; off <<= 1) {
    int tmp = (t >= off) ? lds[t - off] : 0;
    __syncthreads();
    lds[t] += tmp;
    __syncthreads();
  }
  if (idx < V_NODES) g_row_off[idx] = lds[t] - v;   // local exclusive prefix
  if (t == 255) g_blocksum[b] = lds[255];
}

// ---------------- K3b: fused blocksum-scan + offset-add + m2 base walk --------
__global__ __launch_bounds__(256) void scan_bcm_kernel()
{
  __shared__ int lds[256];
  const int b = blockIdx.x, t = threadIdx.x;       // 196 blocks
  // every block redundantly scans the 196 block sums (trivial)
  const int v = (t < SCAN_BLOCKS) ? g_blocksum[t] : 0;
  lds[t] = v;
  __syncthreads();
  for (int off = 1; off < 256; off <<= 1) {
    int tmp = (t >= off) ? lds[t - off] : 0;
    __syncthreads();
    lds[t] += tmp;
    __syncthreads();
  }
  const int total = lds[255];                      // = E
  const int boff  = (b == 0) ? 0 : lds[b - 1];     // exclusive offset of block b
  const int idx = b * 256 + t;
  if (idx < V_NODES) {
    int running = g_row_off[idx] + boff;           // global exclusive prefix
    g_row_off[idx] = running;
    // m2: matrix counts -> segment bases (in-place)
#pragma unroll 7
    for (int c = 0; c < NCHUNK; c++) {
      const unsigned int cnt = g_mat[c * V_NODES + idx];
      g_mat[c * V_NODES + idx] = (unsigned int)running;
      running += (int)cnt;
    }
  }
  if (b == 0 && t == 0) g_row_off[V_NODES] = total;
}

// ---------------- K4: edge scatter — atomic-free, one 8B write/edge ----------
__global__ void edge_scatter_kernel(
    const int* __restrict__ src, const int* __restrict__ dst, int E)
{
  int e = blockIdx.x * blockDim.x + threadIdx.x;
  if (e >= E) return;
  const int d = dst[e], sn = src[e];
  float logit = g_pd[d] + g_ps[sn] + b2f(g_wsmall[OFF_BEDGE]);
  logit = (logit >= 0.f) ? logit : 0.01f * logit;           // LeakyReLU(0.01)
  const float w = __expf(logit);                            // no max-sub: cancels
  const int c = e >> 14;                                    // chunk
  const int pos = (int)g_mat[c * V_NODES + d] + (int)g_rank16[e];
  g_s_pair[pos] = make_int2(sn, __float_as_int(w));
}

// ---------------- K5: aggregation, 12-deep gather pipeline -------------------
__global__ __launch_bounds__(256) void aggregate_kernel()
{
  const int v = blockIdx.x * 4 + (threadIdx.x >> 6);   // grid 12500 -> v < 50000
  const int lane = threadIdx.x & 63;                   // lane: cols 2l, 2l+1
  const int beg = g_row_off[v], end = g_row_off[v + 1];
  float accx = 0.f, accy = 0.f, ssum = 0.f;
  int i = beg;
  for (; i + 12 <= end; i += 12) {     // 12 gathers in flight
    int2 q[12];
#pragma unroll
    for (int j = 0; j < 12; j++) q[j] = g_s_pair[i + j];
    unsigned int p[12];
#pragma unroll
    for (int j = 0; j < 12; j++)
      p[j] = *reinterpret_cast<const unsigned int*>(g_hv + q[j].x * D_FEAT + lane * 2);
#pragma unroll
    for (int j = 0; j < 12; j++) {
      const float w = __int_as_float(q[j].y);
      ssum += w;
      accx += w * b2f((unsigned short)(p[j] & 0xFFFFu));
      accy += w * b2f((unsigned short)(p[j] >> 16));
    }
  }
  for (; i + 4 <= end; i += 4) {       // 4-deep tail
    int2 q[4];
#pragma unroll
    for (int j = 0; j < 4; j++) q[j] = g_s_pair[i + j];
    unsigned int p[4];
#pragma unroll
    for (int j = 0; j < 4; j++)
      p[j] = *reinterpret_cast<const unsigned int*>(g_hv + q[j].x * D_FEAT + lane * 2);
#pragma unroll
    for (int j = 0; j < 4; j++) {
      const float w = __int_as_float(q[j].y);
      ssum += w;
      accx += w * b2f((unsigned short)(p[j] & 0xFFFFu));
      accy += w * b2f((unsigned short)(p[j] >> 16));
    }
  }
  for (; i < end; i++) {
    const int2 q = g_s_pair[i];
    const float w = __int_as_float(q.y);
    ssum += w;
    const unsigned int pair =
        *reinterpret_cast<const unsigned int*>(g_hv + q.x * D_FEAT + lane * 2);
    accx += w * b2f((unsigned short)(pair & 0xFFFFu));
    accy += w * b2f((unsigned short)(pair >> 16));
  }
  const float inv = (end > beg) ? (1.0f / ssum) : 0.0f;     // empty segment -> c=0
  float c0 = accx * inv, c1 = accy * inv;
  c0 = (c0 > 0.f) ? c0 : (__expf(c0) - 1.f);                // elu
  c1 = (c1 > 0.f) ? c1 : (__expf(c1) - 1.f);
  const unsigned int outp = ((unsigned int)f2b(c1) << 16) | (unsigned int)f2b(c0);
  *reinterpret_cast<unsigned int*>(g_ctx + v * D_FEAT + lane * 2) = outp;
}

// ---------------- K6: GRU weight-stationary + XCD swizzle + LDS DMA pipeline --
__global__ __launch_bounds__(256, 2) void gru_kernel(const float* __restrict__ xf32,
                                                     float* __restrict__ out)
{
  // XCD-grouping swizzle (R23/R25-verified): 2 blocks of a chunk on one XCD.
  const int d = blockIdx.x;
  const int x = d & 7;                       // XCD (round-robin dispatch)
  const int s = d >> 3;                      // slot on that XCD [0, 158)
  const int chunk = x + 8 * (s >> 1);        // 2 slots -> same chunk
  if (chunk >= 625) return;                  // block-uniform guard (14 blocks)
  // double-buffered A-tile staging: [buf][x:0-4K | ctx:4K-8K], linear layout,
  // values pre-permuted at stage so swizzled ds_read is conflict-free.
  __shared__ __attribute__((aligned(16))) char lds_s[2][8192];
  __shared__ int pcnt;
  // block-local dtype probe (replaces probe kernel; full block participates)
  const int isb = block_probe(reinterpret_cast<const unsigned int*>(xf32), &pcnt);
  const int half  = s & 1;                   // cg half: 0 -> cg 0..3, 1 -> 4..7
  const int wid   = threadIdx.x >> 6;
  const int lane  = threadIdx.x & 63;
  const int cg    = half * 4 + wid;          // 0..7
  const int col   = lane & 15;
  const int quad  = lane >> 4;
  const int h     = 16 * cg + col;
  const unsigned short* W_ih = g_wsmall + OFF_WIH;
  const unsigned short* W_hh = g_wsmall + OFF_WHH;

  // per-wave constant biases for columns h
  const float br  = b2f(g_wsmall[OFF_BIH + h])       + b2f(g_wsmall[OFF_BHH + h]);
  const float bz  = b2f(g_wsmall[OFF_BIH + 128 + h]) + b2f(g_wsmall[OFF_BHH + 128 + h]);
  const float bn  = b2f(g_wsmall[OFF_BIH + 256 + h]);
  const float bh_ = b2f(g_wsmall[OFF_BHH + 256 + h]);

  // resident B fragments: 24 frags = 96 regs (unified file; launch_bounds(256,2))
  bf16x8 bIHr[4], bHHr[4], bIHz[4], bHHz[4], bIHn[4], bHHn[4];
#pragma unroll
  for (int kk = 0; kk < 4; kk++) {
    const int ko = kk * 32 + quad * 8;
    bIHr[kk] = load_frag(W_ih + h * D_FEAT + ko);
    bHHr[kk] = load_frag(W_hh + h * D_FEAT + ko);
    bIHz[kk] = load_frag(W_ih + (128 + h) * D_FEAT + ko);
    bHHz[kk] = load_frag(W_hh + (128 + h) * D_FEAT + ko);
    bIHn[kk] = load_frag(W_ih + (256 + h) * D_FEAT + ko);
    bHHn[kk] = load_frag(W_hh + (256 + h) * D_FEAT + ko);
  }

  // staging addresses: thread's linear dest offset o in a 4KB tile; the value
  // placed there comes from global offset o ^ ((row&7)<<4) (involution), so a
  // swizzled ds_read returns the logical element (rule #21: both sides).
  const int o_lin = wid * 1024 + lane * 16;                 // dest offset
  const int o_src = o_lin ^ (((o_lin >> 8) & 7) << 4);      // swizzled source
  const char* xbf_b = reinterpret_cast<const char*>(g_xbf);
  const char* ctx_b = reinterpret_cast<const char*>(g_ctx);

  const int t0 = chunk * GCHUNK;
  // prologue: issue DMA for tile t0 into buf 0
  async_copy16(xbf_b + (size_t)t0 * 4096 + o_src, &lds_s[0][wid * 1024]);
  async_copy16(ctx_b + (size_t)t0 * 4096 + o_src, &lds_s[0][4096 + wid * 1024]);

  for (int i = 0; i < GCHUNK; i++) {
    const int t = t0 + i;
    const int buf = i & 1;
    __syncthreads();   // implicit vmcnt(0) drain: buf's DMA complete + visible
    // ds_read frags from staged tile (swizzled, conflict-light)
    bf16x8 ax[4], ac[4];
#pragma unroll
    for (int kk = 0; kk < 4; kk++) {
      const int phys = (col * 256 + kk * 64 + quad * 16) ^ ((col & 7) << 4);
      ax[kk] = *reinterpret_cast<const bf16x8*>(&lds_s[buf][phys]);
      ac[kk] = *reinterpret_cast<const bf16x8*>(&lds_s[buf][4096 + phys]);
    }
    // issue next tile's DMA now (zero-register prefetch; covered by MFMA)
    if (i + 1 < GCHUNK) {
      async_copy16(xbf_b + (size_t)(t + 1) * 4096 + o_src,
                   &lds_s[buf ^ 1][wid * 1024]);
      async_copy16(ctx_b + (size_t)(t + 1) * 4096 + o_src,
                   &lds_s[buf ^ 1][4096 + wid * 1024]);
    }
    // hoisted xv global loads (keep f32 precision path; hidden under MFMAs)
    float xv[4];
    if (isb) {
#pragma unroll
      for (int r = 0; r < 4; r++)
        xv[r] = b2f(g_xbf[(t * 16 + quad * 4 + r) * D_FEAT + h]);
    } else {
#pragma unroll
      for (int r = 0; r < 4; r++)
        xv[r] = xf32[(t * 16 + quad * 4 + r) * D_FEAT + h];
    }
    f32x4 racc, zacc, niacc, nhacc;
    racc[0]=br;  racc[1]=br;  racc[2]=br;  racc[3]=br;
    zacc[0]=bz;  zacc[1]=bz;  zacc[2]=bz;  zacc[3]=bz;
    niacc[0]=bn; niacc[1]=bn; niacc[2]=bn; niacc[3]=bn;
    nhacc[0]=bh_; nhacc[1]=bh_; nhacc[2]=bh_; nhacc[3]=bh_;
#pragma unroll
    for (int kk = 0; kk < 4; kk++) {
      racc  = __builtin_amdgcn_mfma_f32_16x16x32_bf16(ac[kk], bIHr[kk], racc, 0, 0, 0);
      racc  = __builtin_amdgcn_mfma_f32_16x16x32_bf16(ax[kk], bHHr[kk], racc, 0, 0, 0);
      zacc  = __builtin_amdgcn_mfma_f32_16x16x32_bf16(ac[kk], bIHz[kk], zacc, 0, 0, 0);
      zacc  = __builtin_amdgcn_mfma_f32_16x16x32_bf16(ax[kk], bHHz[kk], zacc, 0, 0, 0);
      niacc = __builtin_amdgcn_mfma_f32_16x16x32_bf16(ac[kk], bIHn[kk], niacc, 0, 0, 0);
      nhacc = __builtin_amdgcn_mfma_f32_16x16x32_bf16(ax[kk], bHHn[kk], nhacc, 0, 0, 0);
    }
#pragma unroll
    for (int r = 0; r < 4; r++) {
      const int vrow = t * 16 + quad * 4 + r;
      const float rg = fast_sigmoid(racc[r]);
      const float zg = fast_sigmoid(zacc[r]);
      const float n  = fast_tanh(niacc[r] + rg * nhacc[r]);
      const float hn = (1.f - zg) * n + zg * xv[r];
      out[vrow * D_FEAT + h] = (hn < 0.f) ? 0.f : hn;  // relu; NaN passes (canary)
    }
  }
}

// ---------------- launch ------------------------------------------------------
extern "C" void kernel_launch(void* const* d_in, const int* in_sizes, int n_in,
                              void* d_out, int out_size, void* d_ws, size_t ws_size,
                              hipStream_t stream)
{
  (void)d_ws; (void)ws_size; (void)out_size;

  // resolve inputs by element count (same-size pairs keep dict order)
  int ix = -1, iWe = -1, ibe = -1, iWp = -1, ibp = -1,
      iWih = -1, iWhh = -1, ibih = -1, ibhh = -1, isrc = -1, idst = -1;
  for (int i = 0; i < n_in; i++) {
    const int s = in_sizes[i];
    if      (s == 6400000) ix = i;
    else if (s == 256)     iWe = i;
    else if (s == 1)       ibe = i;
    else if (s == 16384)   iWp = i;
    else if (s == 128)     ibp = i;
    else if (s == 49152)   { if (iWih < 0) iWih = i; else iWhh = i; }
    else if (s == 384)     { if (ibih < 0) ibih = i; else ibhh = i; }
    else if (s == 800000)  { if (isrc < 0) isrc = i; else idst = i; }
  }
  if (ix < 0 || iWe < 0 || ibe < 0 || iWp < 0 || ibp < 0 || iWih < 0 ||
      iWhh < 0 || ibih < 0 || ibhh < 0 || isrc < 0 || idst < 0) {
    ix = 0; iWe = 1; ibe = 2; iWp = 3; ibp = 4;           // dict-order fallback
    iWih = 5; iWhh = 6; ibih = 7; ibhh = 8; isrc = 9; idst = 10;
  }

  const int* src = (const int*)d_in[isrc];
  const int* dst = (const int*)d_in[idst];
  float* out = (float*)d_out;

  conv_hist_kernel<<<CONV_X_BLOCKS + CONV_S_BLOCKS + HISTG, 256, 0, stream>>>(
      d_in[ix], dst,
      d_in[iWe], d_in[iWp], d_in[iWih], d_in[iWhh],
      d_in[ibe], d_in[ibp], d_in[ibih], d_in[ibhh]);
  np_kernel<<<WS_BLOCKS, 256, 0, stream>>>();
  scan_a_kernel<<<SCAN_BLOCKS, 256, 0, stream>>>();
  scan_bcm_kernel<<<SCAN_BLOCKS, 256, 0, stream>>>();
  edge_scatter_kernel<<<HIST_BLOCKS, 256, 0, stream>>>(src, dst, E_EDGES);
  aggregate_kernel<<<V_NODES / 4, 256, 0, stream>>>();
  gru_kernel<<<GRU_BLOCKS, 256, 0, stream>>>((const float*)d_in[ix], out);
}

// Round 19
// 212.557 us; speedup vs baseline: 1.0308x; 1.0308x over previous
//
#include <hip/hip_runtime.h>
#include <hip/hip_bf16.h>

// GNN attention layer. V=50000, E=800000, D=H=128. Inputs f32, OUTPUT f32.
//
// R30: R29 REGRESSED (207->219): folding hist into conv charged its 25 KB
// static LDS to all 6899 blocks + lb(256,2) strangled the BW-bound conv
// sections (same trap as R17); aggregate 12-deep = 8-deep (Occ 60->50,
// depth lever exhausted). Revert to R28 structure exactly (probe kernel,
// LDS-free conv_fused, np_hist fusion for hist||np overlap, 8-deep
// aggregate). Single addition on the known-good base: 4-deep ILP in
// edge_scatter (R19/R27-proven mechanism) - int4 dst/src + ushort4 rank16
// per thread, 4 independent random pd/ps/mat reads in flight. Rest = R28.

#define V_NODES 50000
#define E_EDGES 800000
#define D_FEAT  128
#define GCHUNK  5             // tiles per chunk (625 chunks x 8 cg = 5000 tasks)
#define WS_BLOCKS 1250        // np: 5000 waves / 4 per block
#define GRU_BLOCKS 1264       // gru: 8 xcds x 158 slots (2 blocks/chunk, guard)

#define NCHUNK  49            // ceil(800000/16384) edge chunks
#define CHUNK_E 16384         // edges per chunk (e >> 14)
#define RANGES  4             // node ranges per chunk
#define NODE_R  12500         // nodes per range (25 KB packed LDS histogram)
#define HISTG   (NCHUNK * RANGES)   // 196 hist blocks
#define SCAN_BLOCKS 196       // ceil(50000/256)
#define SCAT_BLOCKS 782       // ceil(800000 / (256*4)) edge-scatter blocks

typedef short bf16x8 __attribute__((ext_vector_type(8)));  // 8 bf16 in 4 VGPRs
typedef float f32x4  __attribute__((ext_vector_type(4)));
typedef unsigned short u16x4 __attribute__((ext_vector_type(4)));

// small-tensor bf16 pool element offsets
#define OFF_WEDGE 0
#define OFF_WPROJ 256
#define OFF_WIH   16640
#define OFF_WHH   65792
#define OFF_BEDGE 114944
#define OFF_BPROJ 114945
#define OFF_BIH   115073
#define OFF_BHH   115457
#define SMALL_TOTAL 115841
#define CONV_X_BLOCKS   6250   // 1.6M u16x4 / 256
#define CONV_S_BLOCKS   453

// ---- device-global scratch (~58 MB; immune to ws_size) ----
__device__ int   g_is_bf16;
__device__ float g_pd[V_NODES];
__device__ float g_ps[V_NODES];
__device__ __attribute__((aligned(16))) unsigned int g_mat[NCHUNK * V_NODES]; // counts -> bases
__device__ int   g_row_off[V_NODES + 1];
__device__ int   g_blocksum[SCAN_BLOCKS];
__device__ unsigned short g_rank16[E_EDGES];    // within-chunk rank
__device__ __attribute__((aligned(16))) int2 g_s_pair[E_EDGES];  // {src, bits(w)}
__device__ __attribute__((aligned(16))) unsigned short g_xbf[V_NODES * D_FEAT];
__device__ __attribute__((aligned(16))) unsigned short g_wsmall[SMALL_TOTAL + 15];
__device__ __attribute__((aligned(16))) unsigned short g_hv[V_NODES * D_FEAT];
__device__ __attribute__((aligned(16))) unsigned short g_ctx[V_NODES * D_FEAT];

static __device__ __forceinline__ float b2f(unsigned short u) {
  union { unsigned int i; float f; } v; v.i = ((unsigned int)u) << 16; return v.f;
}
static __device__ __forceinline__ unsigned short f2b(float f) {
  unsigned int i = __float_as_uint(f);
  unsigned int r = (i + 0x7FFFu + ((i >> 16) & 1u)) >> 16;  // RNE (NaN stays NaN)
  return (unsigned short)r;
}
static __device__ __forceinline__ bf16x8 load_frag(const unsigned short* p) {
  return *reinterpret_cast<const bf16x8*>(p);  // 16B-aligned vector load
}
static __device__ __forceinline__ float fast_rcp(float x) {
  return __builtin_amdgcn_rcpf(x);             // v_rcp_f32, ~1 ulp
}
static __device__ __forceinline__ float fast_sigmoid(float x) {
  return fast_rcp(1.f + __expf(-x));           // x<<0: exp->inf, rcp->0. ok
}
static __device__ __forceinline__ float fast_tanh(float y) {
  // 1 - 2/(e^{2y}+1); y>>0: exp->inf, rcp->0 -> 1; y<<0: exp->0 -> -1; NaN->NaN
  return 1.f - 2.f * fast_rcp(__expf(2.f * y) + 1.f);
}
// async global->LDS DMA, 16B per lane; lds ptr is wave-uniform base
static __device__ __forceinline__ void async_copy16(const void* g, void* l) {
  __builtin_amdgcn_global_load_lds(
      (const __attribute__((address_space(1))) void*)g,
      (__attribute__((address_space(3))) void*)l, 16, 0, 0);
}

// ---------------- P: dtype probe on x ----------------------------------------
__global__ void probe_kernel(const unsigned int* __restrict__ x)
{
  __shared__ int cnt;
  if (threadIdx.x == 0) cnt = 0;
  __syncthreads();
  const unsigned int w  = x[threadIdx.x];
  const unsigned int lo = w & 0xFFFFu;
  const unsigned int ex = (lo >> 7) & 0xFFu;
  if (lo != 0u && ex >= 118u && ex <= 132u) atomicAdd(&cnt, 1);
  __syncthreads();
  if (threadIdx.x == 0) g_is_bf16 = (cnt >= 200) ? 1 : 0;
}

// ---------------- C: fused convert-x | convert-smalls ------------------------
__global__ void conv_fused_kernel(
    const void* __restrict__ x,
    const void* p0, const void* p1, const void* p2, const void* p3,
    const void* p4, const void* p5, const void* p6, const void* p7)
{
  const int b = blockIdx.x;
  if (b < CONV_X_BLOCKS) {
    const int t = b * 256 + threadIdx.x;
    if (g_is_bf16) {
      reinterpret_cast<u16x4*>(g_xbf)[t] = reinterpret_cast<const u16x4*>(x)[t];
    } else {
      const float4 v = reinterpret_cast<const float4*>(x)[t];
      u16x4 o; o.x = f2b(v.x); o.y = f2b(v.y); o.z = f2b(v.z); o.w = f2b(v.w);
      reinterpret_cast<u16x4*>(g_xbf)[t] = o;
    }
  } else {
    const int i = (b - CONV_X_BLOCKS) * 256 + threadIdx.x;
    if (i >= SMALL_TOTAL) return;
    const int offs[9] = {OFF_WEDGE, OFF_WPROJ, OFF_WIH, OFF_WHH,
                         OFF_BEDGE, OFF_BPROJ, OFF_BIH, OFF_BHH, SMALL_TOTAL};
    const void* ps[8] = {p0, p1, p2, p3, p4, p5, p6, p7};
    int r = 0;
#pragma unroll
    for (int k = 0; k < 8; k++) if (i >= offs[k]) r = k;
    const int j = i - offs[r];
    g_wsmall[i] = g_is_bf16
        ? reinterpret_cast<const unsigned short*>(ps[r])[j]
        : f2b(reinterpret_cast<const float*>(ps[r])[j]);
  }
}

// ---------------- K1: hist(c,r) int4-ILP LDS + node_pre (LDS-DMA tiles) ------
__global__ __launch_bounds__(256, 2) void np_hist_kernel(const int* __restrict__ dst)
{
  __shared__ unsigned int hloc[NODE_R / 2];  // 25 KB; 2 node counters per word
  __shared__ __attribute__((aligned(16))) char lds_x[2][4096];  // np x-tile dbuf
  const int b = blockIdx.x;
  if (b < HISTG) {                           // ---- chunk x range histogram ----
    const int c  = b >> 2;                   // chunk [0,49)
    const int r0 = (b & 3) * NODE_R;         // range base node
    for (int i = threadIdx.x; i < NODE_R / 2; i += 256) hloc[i] = 0u;
    __syncthreads();
    const int ebase = c * CHUNK_E;
    const int ecnt  = min(CHUNK_E, E_EDGES - ebase);   // always multiple of 4
    const int4* dst4 = reinterpret_cast<const int4*>(dst + ebase);
    const int n4 = ecnt >> 2;
    for (int i = threadIdx.x; i < n4; i += 256) {
      const int4 d4 = dst4[i];               // 4 edges per thread per iter
      const int e0 = ebase + (i << 2);
      const unsigned int rx = (unsigned int)(d4.x - r0);
      const unsigned int ry = (unsigned int)(d4.y - r0);
      const unsigned int rz = (unsigned int)(d4.z - r0);
      const unsigned int rw = (unsigned int)(d4.w - r0);
      if (rx < (unsigned int)NODE_R) {       // 4 independent atomics pipeline
        const unsigned int sh = (rx & 1u) << 4;
        const unsigned int old = atomicAdd(&hloc[rx >> 1], 1u << sh);
        g_rank16[e0] = (unsigned short)((old >> sh) & 0xFFFFu);
      }
      if (ry < (unsigned int)NODE_R) {
        const unsigned int sh = (ry & 1u) << 4;
        const unsigned int old = atomicAdd(&hloc[ry >> 1], 1u << sh);
        g_rank16[e0 + 1] = (unsigned short)((old >> sh) & 0xFFFFu);
      }
      if (rz < (unsigned int)NODE_R) {
        const unsigned int sh = (rz & 1u) << 4;
        const unsigned int old = atomicAdd(&hloc[rz >> 1], 1u << sh);
        g_rank16[e0 + 2] = (unsigned short)((old >> sh) & 0xFFFFu);
      }
      if (rw < (unsigned int)NODE_R) {
        const unsigned int sh = (rw & 1u) << 4;
        const unsigned int old = atomicAdd(&hloc[rw >> 1], 1u << sh);
        g_rank16[e0 + 3] = (unsigned short)((old >> sh) & 0xFFFFu);
      }
    }
    __syncthreads();
    // vectorized writeout: one hloc word -> uint2 {lo count, hi count}
    uint2* mout = reinterpret_cast<uint2*>(&g_mat[c * V_NODES + r0]);
    for (int i = threadIdx.x; i < NODE_R / 2; i += 256) {
      const unsigned int w = hloc[i];
      mout[i] = make_uint2(w & 0xFFFFu, w >> 16);
    }
    return;
  }
  // ---- node_pre: 4 waves share one chunk (g=4m+wid -> chunk block-uniform) --
  const int wid   = threadIdx.x >> 6;
  const int g     = (b - HISTG) * 4 + wid;
  const int lane  = threadIdx.x & 63;
  const int cg    = g & 7;
  const int chunk = g >> 3;                  // [0, 625), block-uniform
  const int col   = lane & 15;
  const int quad  = lane >> 4;
  const int h     = 16 * cg + col;

  // resident B fragments: W_proj rows [16cg, 16cg+16)
  bf16x8 bw[4];
#pragma unroll
  for (int kk = 0; kk < 4; kk++)
    bw[kk] = load_frag(g_wsmall + OFF_WPROJ + h * D_FEAT + kk * 32 + quad * 8);
  // cg 0 also owns the edge projections (cols 0/1 of W_edge)
  bf16x8 be[4];
#pragma unroll
  for (int kk = 0; kk < 4; kk++) { be[kk] = bf16x8{0,0,0,0,0,0,0,0}; }
  if (cg == 0 && col < 2) {
#pragma unroll
    for (int kk = 0; kk < 4; kk++)
      be[kk] = load_frag(g_wsmall + OFF_WEDGE + col * D_FEAT + kk * 32 + quad * 8);
  }
  const float bp = b2f(g_wsmall[OFF_BPROJ + h]);

  // staging addresses (R26-verified involution): linear LDS dest, swizzled
  // global source, swizzled ds_read returns the logical element.
  const int o_lin = wid * 1024 + lane * 16;
  const int o_src = o_lin ^ (((o_lin >> 8) & 7) << 4);
  const char* xbf_b = reinterpret_cast<const char*>(g_xbf);

  const int t0 = chunk * GCHUNK;
  async_copy16(xbf_b + (size_t)t0 * 4096 + o_src, &lds_x[0][wid * 1024]);

  for (int i = 0; i < GCHUNK; i++) {
    const int t = t0 + i;
    const int buf = i & 1;
    __syncthreads();   // implicit vmcnt(0): buf's DMA complete + visible
    bf16x8 a[4];
#pragma unroll
    for (int kk = 0; kk < 4; kk++) {
      const int phys = (col * 256 + kk * 64 + quad * 16) ^ ((col & 7) << 4);
      a[kk] = *reinterpret_cast<const bf16x8*>(&lds_x[buf][phys]);
    }
    if (i + 1 < GCHUNK)
      async_copy16(xbf_b + (size_t)(t + 1) * 4096 + o_src,
                   &lds_x[buf ^ 1][wid * 1024]);
    f32x4 acc; acc[0]=0.f; acc[1]=0.f; acc[2]=0.f; acc[3]=0.f;
#pragma unroll
    for (int kk = 0; kk < 4; kk++)
      acc = __builtin_amdgcn_mfma_f32_16x16x32_bf16(a[kk], bw[kk], acc, 0, 0, 0);
#pragma unroll
    for (int r = 0; r < 4; r++)
      g_hv[(t * 16 + quad * 4 + r) * D_FEAT + h] = f2b(acc[r] + bp);
    if (cg == 0) {
      f32x4 acce; acce[0]=0.f; acce[1]=0.f; acce[2]=0.f; acce[3]=0.f;
#pragma unroll
      for (int kk = 0; kk < 4; kk++)
        acce = __builtin_amdgcn_mfma_f32_16x16x32_bf16(a[kk], be[kk], acce, 0, 0, 0);
      if (col == 0) {
#pragma unroll
        for (int r = 0; r < 4; r++) g_pd[t * 16 + quad * 4 + r] = acce[r];
      } else if (col == 1) {
#pragma unroll
        for (int r = 0; r < 4; r++) g_ps[t * 16 + quad * 4 + r] = acce[r];
      }
    }
  }
}

// ---------------- K3a: column-sum over chunks + block-local scan --------------
__global__ __launch_bounds__(256) void scan_a_kernel()
{
  __shared__ int lds[256];
  const int b = blockIdx.x, t = threadIdx.x;
  const int idx = b * 256 + t;
  int v = 0;
  if (idx < V_NODES) {
#pragma unroll 7
    for (int c = 0; c < NCHUNK; c++) v += (int)g_mat[c * V_NODES + idx];
  }
  lds[t] = v;
  __syncthreads();
  for (int off = 1; off < 256; off <<= 1) {
    int tmp = (t >= off) ? lds[t - off] : 0;
    __syncthreads();
    lds[t] += tmp;
    __syncthreads();
  }
  if (idx < V_NODES) g_row_off[idx] = lds[t] - v;   // local exclusive prefix
  if (t == 255) g_blocksum[b] = lds[255];
}

// ---------------- K3b: fused blocksum-scan + offset-add + m2 base walk --------
__global__ __launch_bounds__(256) void scan_bcm_kernel()
{
  __shared__ int lds[256];
  const int b = blockIdx.x, t = threadIdx.x;       // 196 blocks
  // every block redundantly scans the 196 block sums (trivial)
  const int v = (t < SCAN_BLOCKS) ? g_blocksum[t] : 0;
  lds[t] = v;
  __syncthreads();
  for (int off = 1; off < 256; off <<= 1) {
    int tmp = (t >= off) ? lds[t - off] : 0;
    __syncthreads();
    lds[t] += tmp;
    __syncthreads();
  }
  const int total = lds[255];                      // = E
  const int boff  = (b == 0) ? 0 : lds[b - 1];     // exclusive offset of block b
  const int idx = b * 256 + t;
  if (idx < V_NODES) {
    int running = g_row_off[idx] + boff;           // global exclusive prefix
    g_row_off[idx] = running;
    // m2: matrix counts -> segment bases (in-place)
#pragma unroll 7
    for (int c = 0; c < NCHUNK; c++) {
      const unsigned int cnt = g_mat[c * V_NODES + idx];
      g_mat[c * V_NODES + idx] = (unsigned int)running;
      running += (int)cnt;
    }
  }
  if (b == 0 && t == 0) g_row_off[V_NODES] = total;
}

// ---------------- K4: edge scatter — 4-deep ILP, one 8B write/edge -----------
__global__ void edge_scatter_kernel(
    const int* __restrict__ src, const int* __restrict__ dst, int E)
{
  const int e0 = (blockIdx.x * blockDim.x + threadIdx.x) << 2;   // 4 edges/thread
  if (e0 >= E) return;                       // E % 4 == 0 -> all-or-nothing
  const int4 d4 = *reinterpret_cast<const int4*>(dst + e0);
  const int4 s4 = *reinterpret_cast<const int4*>(src + e0);
  const u16x4 r4 = *reinterpret_cast<const u16x4*>(g_rank16 + e0);
  const float be = b2f(g_wsmall[OFF_BEDGE]);
  const int c = e0 >> 14;                    // chunk (block of 16384 -> uniform)
  const int dd[4] = {d4.x, d4.y, d4.z, d4.w};
  const int ss[4] = {s4.x, s4.y, s4.z, s4.w};
  // issue 12 independent random reads (pd/ps/mat x4) before any epilogue
  float pd[4], ps[4]; unsigned int mb[4];
#pragma unroll
  for (int j = 0; j < 4; j++) {
    pd[j] = g_pd[dd[j]];
    ps[j] = g_ps[ss[j]];
    mb[j] = g_mat[c * V_NODES + dd[j]];
  }
#pragma unroll
  for (int j = 0; j < 4; j++) {
    float logit = pd[j] + ps[j] + be;
    logit = (logit >= 0.f) ? logit : 0.01f * logit;         // LeakyReLU(0.01)
    const float w = __expf(logit);                          // no max-sub: cancels
    const int pos = (int)mb[j] + (int)r4[j];
    g_s_pair[pos] = make_int2(ss[j], __float_as_int(w));
  }
}

// ---------------- K5: aggregation, 8-deep gather pipeline --------------------
__global__ __launch_bounds__(256) void aggregate_kernel()
{
  const int v = blockIdx.x * 4 + (threadIdx.x >> 6);   // grid 12500 -> v < 50000
  const int lane = threadIdx.x & 63;                   // lane: cols 2l, 2l+1
  const int beg = g_row_off[v], end = g_row_off[v + 1];
  float accx = 0.f, accy = 0.f, ssum = 0.f;
  int i = beg;
  for (; i + 8 <= end; i += 8) {       // 8 gathers in flight
    int2 q[8];
#pragma unroll
    for (int j = 0; j < 8; j++) q[j] = g_s_pair[i + j];
    unsigned int p[8];
#pragma unroll
    for (int j = 0; j < 8; j++)
      p[j] = *reinterpret_cast<const unsigned int*>(g_hv + q[j].x * D_FEAT + lane * 2);
#pragma unroll
    for (int j = 0; j < 8; j++) {
      const float w = __int_as_float(q[j].y);
      ssum += w;
      accx += w * b2f((unsigned short)(p[j] & 0xFFFFu));
      accy += w * b2f((unsigned short)(p[j] >> 16));
    }
  }
  for (; i + 4 <= end; i += 4) {       // 4-deep tail
    int2 q[4];
#pragma unroll
    for (int j = 0; j < 4; j++) q[j] = g_s_pair[i + j];
    unsigned int p[4];
#pragma unroll
    for (int j = 0; j < 4; j++)
      p[j] = *reinterpret_cast<const unsigned int*>(g_hv + q[j].x * D_FEAT + lane * 2);
#pragma unroll
    for (int j = 0; j < 4; j++) {
      const float w = __int_as_float(q[j].y);
      ssum += w;
      accx += w * b2f((unsigned short)(p[j] & 0xFFFFu));
      accy += w * b2f((unsigned short)(p[j] >> 16));
    }
  }
  for (; i < end; i++) {
    const int2 q = g_s_pair[i];
    const float w = __int_as_float(q.y);
    ssum += w;
    const unsigned int pair =
        *reinterpret_cast<const unsigned int*>(g_hv + q.x * D_FEAT + lane * 2);
    accx += w * b2f((unsigned short)(pair & 0xFFFFu));
    accy += w * b2f((unsigned short)(pair >> 16));
  }
  const float inv = (end > beg) ? (1.0f / ssum) : 0.0f;     // empty segment -> c=0
  float c0 = accx * inv, c1 = accy * inv;
  c0 = (c0 > 0.f) ? c0 : (__expf(c0) - 1.f);                // elu
  c1 = (c1 > 0.f) ? c1 : (__expf(c1) - 1.f);
  const unsigned int outp = ((unsigned int)f2b(c1) << 16) | (unsigned int)f2b(c0);
  *reinterpret_cast<unsigned int*>(g_ctx + v * D_FEAT + lane * 2) = outp;
}

// ---------------- K6: GRU weight-stationary + XCD swizzle + LDS DMA pipeline --
__global__ __launch_bounds__(256, 2) void gru_kernel(const float* __restrict__ xf32,
                                                     float* __restrict__ out)
{
  // XCD-grouping swizzle (R23/R25-verified): 2 blocks of a chunk on one XCD.
  const int d = blockIdx.x;
  const int x = d & 7;                       // XCD (round-robin dispatch)
  const int s = d >> 3;                      // slot on that XCD [0, 158)
  const int chunk = x + 8 * (s >> 1);        // 2 slots -> same chunk
  if (chunk >= 625) return;                  // block-uniform guard (14 blocks)
  // double-buffered A-tile staging: [buf][x:0-4K | ctx:4K-8K], linear layout,
  // values pre-permuted at stage so swizzled ds_read is conflict-free.
  __shared__ __attribute__((aligned(16))) char lds_s[2][8192];
  const int half  = s & 1;                   // cg half: 0 -> cg 0..3, 1 -> 4..7
  const int wid   = threadIdx.x >> 6;
  const int lane  = threadIdx.x & 63;
  const int cg    = half * 4 + wid;          // 0..7
  const int col   = lane & 15;
  const int quad  = lane >> 4;
  const int h     = 16 * cg + col;
  const unsigned short* W_ih = g_wsmall + OFF_WIH;
  const unsigned short* W_hh = g_wsmall + OFF_WHH;
  const int isb = g_is_bf16;

  // per-wave constant biases for columns h
  const float br  = b2f(g_wsmall[OFF_BIH + h])       + b2f(g_wsmall[OFF_BHH + h]);
  const float bz  = b2f(g_wsmall[OFF_BIH + 128 + h]) + b2f(g_wsmall[OFF_BHH + 128 + h]);
  const float bn  = b2f(g_wsmall[OFF_BIH + 256 + h]);
  const float bh_ = b2f(g_wsmall[OFF_BHH + 256 + h]);

  // resident B fragments: 24 frags = 96 regs (unified file; launch_bounds(256,2))
  bf16x8 bIHr[4], bHHr[4], bIHz[4], bHHz[4], bIHn[4], bHHn[4];
#pragma unroll
  for (int kk = 0; kk < 4; kk++) {
    const int ko = kk * 32 + quad * 8;
    bIHr[kk] = load_frag(W_ih + h * D_FEAT + ko);
    bHHr[kk] = load_frag(W_hh + h * D_FEAT + ko);
    bIHz[kk] = load_frag(W_ih + (128 + h) * D_FEAT + ko);
    bHHz[kk] = load_frag(W_hh + (128 + h) * D_FEAT + ko);
    bIHn[kk] = load_frag(W_ih + (256 + h) * D_FEAT + ko);
    bHHn[kk] = load_frag(W_hh + (256 + h) * D_FEAT + ko);
  }

  // staging addresses: thread's linear dest offset o in a 4KB tile; the value
  // placed there comes from global offset o ^ ((row&7)<<4) (involution), so a
  // swizzled ds_read returns the logical element (rule #21: both sides).
  const int o_lin = wid * 1024 + lane * 16;                 // dest offset
  const int o_src = o_lin ^ (((o_lin >> 8) & 7) << 4);      // swizzled source
  const char* xbf_b = reinterpret_cast<const char*>(g_xbf);
  const char* ctx_b = reinterpret_cast<const char*>(g_ctx);

  const int t0 = chunk * GCHUNK;
  // prologue: issue DMA for tile t0 into buf 0
  async_copy16(xbf_b + (size_t)t0 * 4096 + o_src, &lds_s[0][wid * 1024]);
  async_copy16(ctx_b + (size_t)t0 * 4096 + o_src, &lds_s[0][4096 + wid * 1024]);

  for (int i = 0; i < GCHUNK; i++) {
    const int t = t0 + i;
    const int buf = i & 1;
    __syncthreads();   // implicit vmcnt(0) drain: buf's DMA complete + visible
    // ds_read frags from staged tile (swizzled, conflict-light)
    bf16x8 ax[4], ac[4];
#pragma unroll
    for (int kk = 0; kk < 4; kk++) {
      const int phys = (col * 256 + kk * 64 + quad * 16) ^ ((col & 7) << 4);
      ax[kk] = *reinterpret_cast<const bf16x8*>(&lds_s[buf][phys]);
      ac[kk] = *reinterpret_cast<const bf16x8*>(&lds_s[buf][4096 + phys]);
    }
    // issue next tile's DMA now (zero-register prefetch; covered by MFMA)
    if (i + 1 < GCHUNK) {
      async_copy16(xbf_b + (size_t)(t + 1) * 4096 + o_src,
                   &lds_s[buf ^ 1][wid * 1024]);
      async_copy16(ctx_b + (size_t)(t + 1) * 4096 + o_src,
                   &lds_s[buf ^ 1][4096 + wid * 1024]);
    }
    // hoisted xv global loads (keep f32 precision path; hidden under MFMAs)
    float xv[4];
    if (isb) {
#pragma unroll
      for (int r = 0; r < 4; r++)
        xv[r] = b2f(g_xbf[(t * 16 + quad * 4 + r) * D_FEAT + h]);
    } else {
#pragma unroll
      for (int r = 0; r < 4; r++)
        xv[r] = xf32[(t * 16 + quad * 4 + r) * D_FEAT + h];
    }
    f32x4 racc, zacc, niacc, nhacc;
    racc[0]=br;  racc[1]=br;  racc[2]=br;  racc[3]=br;
    zacc[0]=bz;  zacc[1]=bz;  zacc[2]=bz;  zacc[3]=bz;
    niacc[0]=bn; niacc[1]=bn; niacc[2]=bn; niacc[3]=bn;
    nhacc[0]=bh_; nhacc[1]=bh_; nhacc[2]=bh_; nhacc[3]=bh_;
#pragma unroll
    for (int kk = 0; kk < 4; kk++) {
      racc  = __builtin_amdgcn_mfma_f32_16x16x32_bf16(ac[kk], bIHr[kk], racc, 0, 0, 0);
      racc  = __builtin_amdgcn_mfma_f32_16x16x32_bf16(ax[kk], bHHr[kk], racc, 0, 0, 0);
      zacc  = __builtin_amdgcn_mfma_f32_16x16x32_bf16(ac[kk], bIHz[kk], zacc, 0, 0, 0);
      zacc  = __builtin_amdgcn_mfma_f32_16x16x32_bf16(ax[kk], bHHz[kk], zacc, 0, 0, 0);
      niacc = __builtin_amdgcn_mfma_f32_16x16x32_bf16(ac[kk], bIHn[kk], niacc, 0, 0, 0);
      nhacc = __builtin_amdgcn_mfma_f32_16x16x32_bf16(ax[kk], bHHn[kk], nhacc, 0, 0, 0);
    }
#pragma unroll
    for (int r = 0; r < 4; r++) {
      const int vrow = t * 16 + quad * 4 + r;
      const float rg = fast_sigmoid(racc[r]);
      const float zg = fast_sigmoid(zacc[r]);
      const float n  = fast_tanh(niacc[r] + rg * nhacc[r]);
      const float hn = (1.f - zg) * n + zg * xv[r];
      out[vrow * D_FEAT + h] = (hn < 0.f) ? 0.f : hn;  // relu; NaN passes (canary)
    }
  }
}

// ---------------- launch ------------------------------------------------------
extern "C" void kernel_launch(void* const* d_in, const int* in_sizes, int n_in,
                              void* d_out, int out_size, void* d_ws, size_t ws_size,
                              hipStream_t stream)
{
  (void)d_ws; (void)ws_size; (void)out_size;

  // resolve inputs by element count (same-size pairs keep dict order)
  int ix = -1, iWe = -1, ibe = -1, iWp = -1, ibp = -1,
      iWih = -1, iWhh = -1, ibih = -1, ibhh = -1, isrc = -1, idst = -1;
  for (int i = 0; i < n_in; i++) {
    const int s = in_sizes[i];
    if      (s == 6400000) ix = i;
    else if (s == 256)     iWe = i;
    else if (s == 1)       ibe = i;
    else if (s == 16384)   iWp = i;
    else if (s == 128)     ibp = i;
    else if (s == 49152)   { if (iWih < 0) iWih = i; else iWhh = i; }
    else if (s == 384)     { if (ibih < 0) ibih = i; else ibhh = i; }
    else if (s == 800000)  { if (isrc < 0) isrc = i; else idst = i; }
  }
  if (ix < 0 || iWe < 0 || ibe < 0 || iWp < 0 || ibp < 0 || iWih < 0 ||
      iWhh < 0 || ibih < 0 || ibhh < 0 || isrc < 0 || idst < 0) {
    ix = 0; iWe = 1; ibe = 2; iWp = 3; ibp = 4;           // dict-order fallback
    iWih = 5; iWhh = 6; ibih = 7; ibhh = 8; isrc = 9; idst = 10;
  }

  const int* src = (const int*)d_in[isrc];
  const int* dst = (const int*)d_in[idst];
  float* out = (float*)d_out;

  probe_kernel<<<1, 256, 0, stream>>>((const unsigned int*)d_in[ix]);
  conv_fused_kernel<<<CONV_X_BLOCKS + CONV_S_BLOCKS, 256, 0, stream>>>(
      d_in[ix],
      d_in[iWe], d_in[iWp], d_in[iWih], d_in[iWhh],
      d_in[ibe], d_in[ibp], d_in[ibih], d_in[ibhh]);
  np_hist_kernel<<<HISTG + WS_BLOCKS, 256, 0, stream>>>(dst);
  scan_a_kernel<<<SCAN_BLOCKS, 256, 0, stream>>>();
  scan_bcm_kernel<<<SCAN_BLOCKS, 256, 0, stream>>>();
  edge_scatter_kernel<<<SCAT_BLOCKS, 256, 0, stream>>>(src, dst, E_EDGES);
  aggregate_kernel<<<V_NODES / 4, 256, 0, stream>>>();
  gru_kernel<<<GRU_BLOCKS, 256, 0, stream>>>((const float*)d_in[ix], out);
}